// Round 3
// baseline (900.382 us; speedup 1.0000x reference)
//
#include <hip/hip_runtime.h>

#define FIN 128
#define HID 64
#define OUTC 16

// ---------------- K1: h1 = x @ W1 ; as1/ad1 = rowdot(h1, a_src/a_dst) ----------------
__global__ __launch_bounds__(256) void k1_gemm1(
    const float* __restrict__ x, const float* __restrict__ W1,
    const float* __restrict__ a_src, const float* __restrict__ a_dst,
    float* __restrict__ h1, float* __restrict__ as1, float* __restrict__ ad1, int N)
{
    __shared__ float Wlds[FIN * HID];   // 32 KB
    __shared__ float xlds[4 * FIN];     // 2 KB
    int tid = threadIdx.x;
    for (int i = tid; i < FIN * HID; i += 256) Wlds[i] = W1[i];
    int row0 = blockIdx.x * 4;
    for (int i = tid; i < 4 * FIN; i += 256) {
        int r = row0 + (i >> 7);
        xlds[i] = (r < N) ? x[(size_t)r * FIN + (i & 127)] : 0.f;
    }
    __syncthreads();
    int col = tid & 63;        // channel
    int wl  = tid >> 6;        // wave index = local row
    int row = row0 + wl;
    float acc = 0.f;
    #pragma unroll 8
    for (int k = 0; k < FIN; ++k)
        acc += xlds[wl * FIN + k] * Wlds[k * HID + col];
    if (row < N) {
        h1[(size_t)row * HID + col] = acc;
        float vs = acc * a_src[col];
        float vd = acc * a_dst[col];
        for (int off = 32; off > 0; off >>= 1) {
            vs += __shfl_down(vs, off);
            vd += __shfl_down(vd, off);
        }
        if (col == 0) { as1[row] = vs; ad1[row] = vd; }
    }
}

// ---------------- edge pass A: w = exp(leaky_relu(as[s]+ad[d])), denom[d] += w -------
__global__ __launch_bounds__(256) void k_edgeA(
    const int* __restrict__ ei, const float* __restrict__ as, const float* __restrict__ ad,
    float* __restrict__ ew, float* __restrict__ denom, int E, int N)
{
    int e = blockIdx.x * 256 + threadIdx.x;
    int tot = E + N;
    if (e >= tot) return;
    int s, d;
    if (e < E) { s = ei[e]; d = ei[E + e]; } else { s = d = e - E; }
    float v = as[s] + ad[d];
    v = (v > 0.f) ? v : 0.2f * v;
    float w = __expf(v);
    ew[e] = w;
    atomicAdd(&denom[d], w);
}

// ---------------- edge pass B, C=64: one wave per edge -------------------------------
__global__ __launch_bounds__(256) void k_edgeB64(
    const int* __restrict__ ei, const float* __restrict__ ew, const float* __restrict__ denom,
    const float* __restrict__ h, float* __restrict__ outacc, int E, int N)
{
    int lane = threadIdx.x & 63;
    int e = blockIdx.x * 4 + (threadIdx.x >> 6);
    int tot = E + N;
    if (e >= tot) return;
    int s, d;
    if (e < E) { s = ei[e]; d = ei[E + e]; } else { s = d = e - E; }
    float alpha = ew[e] / (denom[d] + 1e-16f);
    float val = h[(size_t)s * HID + lane] * alpha;
    atomicAdd(&outacc[(size_t)d * HID + lane], val);
}

// ---------------- K4: relu(out1+b1) @ W2 ; as2/ad2 -----------------------------------
__global__ __launch_bounds__(256) void k4_gemm2(
    const float* __restrict__ out1, const float* __restrict__ b1,
    const float* __restrict__ W2, const float* __restrict__ a_src, const float* __restrict__ a_dst,
    float* __restrict__ h2, float* __restrict__ as2, float* __restrict__ ad2, int N)
{
    __shared__ float Wlds[HID * OUTC];   // 4 KB
    __shared__ float rlds[16 * HID];     // 4 KB
    int tid = threadIdx.x;
    for (int i = tid; i < HID * OUTC; i += 256) Wlds[i] = W2[i];
    int row0 = blockIdx.x * 16;
    for (int i = tid; i < 16 * HID; i += 256) {
        int r = row0 + (i >> 6);
        float v = (r < N) ? out1[(size_t)r * HID + (i & 63)] : 0.f;
        v += b1[i & 63];
        rlds[i] = fmaxf(v, 0.f);
    }
    __syncthreads();
    int col = tid & 15;
    int rl  = tid >> 4;
    int row = row0 + rl;
    float acc = 0.f;
    #pragma unroll 8
    for (int k = 0; k < HID; ++k)
        acc += rlds[rl * HID + k] * Wlds[k * OUTC + col];
    if (row < N) {
        h2[(size_t)row * OUTC + col] = acc;
        float vs = acc * a_src[col];
        float vd = acc * a_dst[col];
        for (int off = 8; off > 0; off >>= 1) {
            vs += __shfl_down(vs, off, 16);
            vd += __shfl_down(vd, off, 16);
        }
        if (col == 0) { as2[row] = vs; ad2[row] = vd; }
    }
}

// ---------------- edge pass B, C=16: 16 lanes per edge -------------------------------
__global__ __launch_bounds__(256) void k_edgeB16(
    const int* __restrict__ ei, const float* __restrict__ ew, const float* __restrict__ denom,
    const float* __restrict__ h, float* __restrict__ outacc, int E, int N)
{
    int lane = threadIdx.x & 15;
    int e = blockIdx.x * 16 + (threadIdx.x >> 4);
    int tot = E + N;
    if (e >= tot) return;
    int s, d;
    if (e < E) { s = ei[e]; d = ei[E + e]; } else { s = d = e - E; }
    float alpha = ew[e] / (denom[d] + 1e-16f);
    float val = h[(size_t)s * OUTC + lane] * alpha;
    atomicAdd(&outacc[(size_t)d * OUTC + lane], val);
}

// ---------------- K7: per-node MLP 16->64->16 + softmax ------------------------------
__global__ __launch_bounds__(256) void k7_mlp(
    const float* __restrict__ out2, const float* __restrict__ b2,
    const float* __restrict__ lin1W, const float* __restrict__ lin1b,
    const float* __restrict__ lin2W, const float* __restrict__ lin2b,
    float* __restrict__ out, int N)
{
    __shared__ float W1l[OUTC * HID];   // 4 KB
    __shared__ float W2l[HID * OUTC];   // 4 KB
    __shared__ float b1l[HID], bb2[OUTC], b2l[OUTC];
    int tid = threadIdx.x;
    for (int i = tid; i < OUTC * HID; i += 256) { W1l[i] = lin1W[i]; W2l[i] = lin2W[i]; }
    if (tid < HID) b1l[tid] = lin1b[tid];
    if (tid < OUTC) { bb2[tid] = b2[tid]; b2l[tid] = lin2b[tid]; }
    __syncthreads();
    int n = blockIdx.x * 256 + tid;
    if (n >= N) return;

    float o[OUTC];
    const float4* o4 = (const float4*)(out2 + (size_t)n * OUTC);
    #pragma unroll
    for (int i = 0; i < 4; ++i) {
        float4 v = o4[i];
        o[4*i+0] = v.x + bb2[4*i+0];
        o[4*i+1] = v.y + bb2[4*i+1];
        o[4*i+2] = v.z + bb2[4*i+2];
        o[4*i+3] = v.w + bb2[4*i+3];
    }
    float u[OUTC];
    #pragma unroll
    for (int c = 0; c < OUTC; ++c) u[c] = b2l[c];
    for (int j = 0; j < HID; ++j) {
        float t = b1l[j];
        #pragma unroll
        for (int i = 0; i < OUTC; ++i) t += o[i] * W1l[i * HID + j];
        t = fmaxf(t, 0.f);
        #pragma unroll
        for (int c = 0; c < OUTC; ++c) u[c] += t * W2l[j * OUTC + c];
    }
    float m = u[0];
    #pragma unroll
    for (int c = 1; c < OUTC; ++c) m = fmaxf(m, u[c]);
    float sum = 0.f;
    #pragma unroll
    for (int c = 0; c < OUTC; ++c) { u[c] = __expf(u[c] - m); sum += u[c]; }
    float inv = 1.f / sum;
    float4* dst4 = (float4*)(out + (size_t)n * OUTC);
    #pragma unroll
    for (int i = 0; i < 4; ++i) {
        float4 v;
        v.x = u[4*i+0] * inv; v.y = u[4*i+1] * inv;
        v.z = u[4*i+2] * inv; v.w = u[4*i+3] * inv;
        dst4[i] = v;
    }
}

extern "C" void kernel_launch(void* const* d_in, const int* in_sizes, int n_in,
                              void* d_out, int out_size, void* d_ws, size_t ws_size,
                              hipStream_t stream)
{
    const float* x      = (const float*)d_in[0];
    const int*   ei     = (const int*)  d_in[1];
    const float* W1     = (const float*)d_in[2];
    const float* a_src1 = (const float*)d_in[3];
    const float* a_dst1 = (const float*)d_in[4];
    const float* b1     = (const float*)d_in[5];
    const float* W2     = (const float*)d_in[6];
    const float* a_src2 = (const float*)d_in[7];
    const float* a_dst2 = (const float*)d_in[8];
    const float* b2     = (const float*)d_in[9];
    const float* lin1W  = (const float*)d_in[10];
    const float* lin1b  = (const float*)d_in[11];
    const float* lin2W  = (const float*)d_in[12];
    const float* lin2b  = (const float*)d_in[13];
    float* out = (float*)d_out;

    int N = in_sizes[0] / FIN;
    int E = in_sizes[1] / 2;
    int tot = E + N;

    float* ws = (float*)d_ws;
    size_t off = 0;
    float* h1    = ws + off; off += (size_t)N * HID;
    float* out1  = ws + off; off += (size_t)N * HID;
    float* as1   = ws + off; off += N;
    float* ad1   = ws + off; off += N;
    float* denom = ws + off; off += N;
    float* ew    = ws + off; off += tot;
    float* h2    = ws + off; off += (size_t)N * OUTC;
    float* as2   = ws + off; off += N;
    float* ad2   = ws + off; off += N;
    float* out2  = ws + off; off += (size_t)N * OUTC;

    hipMemsetAsync(denom, 0, (size_t)N * sizeof(float), stream);
    hipMemsetAsync(out1,  0, (size_t)N * HID * sizeof(float), stream);
    hipMemsetAsync(out2,  0, (size_t)N * OUTC * sizeof(float), stream);

    k1_gemm1<<<(N + 3) / 4, 256, 0, stream>>>(x, W1, a_src1, a_dst1, h1, as1, ad1, N);
    k_edgeA<<<(tot + 255) / 256, 256, 0, stream>>>(ei, as1, ad1, ew, denom, E, N);
    k_edgeB64<<<(tot + 3) / 4, 256, 0, stream>>>(ei, ew, denom, h1, out1, E, N);
    k4_gemm2<<<(N + 15) / 16, 256, 0, stream>>>(out1, b1, W2, a_src2, a_dst2, h2, as2, ad2, N);
    hipMemsetAsync(denom, 0, (size_t)N * sizeof(float), stream);
    k_edgeA<<<(tot + 255) / 256, 256, 0, stream>>>(ei, as2, ad2, ew, denom, E, N);
    k_edgeB16<<<(tot + 15) / 16, 256, 0, stream>>>(ei, ew, denom, h2, out2, E, N);
    k7_mlp<<<(N + 255) / 256, 256, 0, stream>>>(out2, b2, lin1W, lin1b, lin2W, lin2b, out, N);
}

// Round 6
// 684.175 us; speedup vs baseline: 1.3160x; 1.3160x over previous
//
#include <hip/hip_runtime.h>

#define FIN 128
#define HID 64
#define OUTC 16

// ---------------- K1: h1 = x @ W1 ; as1/ad1 = rowdot(h1, a_src/a_dst) ----------------
__global__ __launch_bounds__(256) void k1_gemm1(
    const float* __restrict__ x, const float* __restrict__ W1,
    const float* __restrict__ a_src, const float* __restrict__ a_dst,
    float* __restrict__ h1, float* __restrict__ as1, float* __restrict__ ad1, int N)
{
    __shared__ float Wlds[FIN * HID];   // 32 KB
    __shared__ float xlds[4 * FIN];     // 2 KB
    int tid = threadIdx.x;
    for (int i = tid; i < FIN * HID; i += 256) Wlds[i] = W1[i];
    int row0 = blockIdx.x * 4;
    for (int i = tid; i < 4 * FIN; i += 256) {
        int r = row0 + (i >> 7);
        xlds[i] = (r < N) ? x[(size_t)r * FIN + (i & 127)] : 0.f;
    }
    __syncthreads();
    int col = tid & 63;        // channel
    int wl  = tid >> 6;        // wave index = local row
    int row = row0 + wl;
    float acc = 0.f;
    #pragma unroll 8
    for (int k = 0; k < FIN; ++k)
        acc += xlds[wl * FIN + k] * Wlds[k * HID + col];
    if (row < N) {
        h1[(size_t)row * HID + col] = acc;
        float vs = acc * a_src[col];
        float vd = acc * a_dst[col];
        for (int off = 32; off > 0; off >>= 1) {
            vs += __shfl_down(vs, off);
            vd += __shfl_down(vd, off);
        }
        if (col == 0) { as1[row] = vs; ad1[row] = vd; }
    }
}

// ---------------- CSR build: histogram of dst --------------------------------------
__global__ __launch_bounds__(256) void k_hist(
    const int* __restrict__ ei, int* __restrict__ counts, int E, int N)
{
    int e = blockIdx.x * 256 + threadIdx.x;
    int tot = E + N;
    if (e >= tot) return;
    int d = (e < E) ? ei[E + e] : (e - E);
    atomicAdd(&counts[d], 1);
}

// ---------------- CSR build: segment allocation (order-free "scan") -----------------
// rowstart[d] = disjoint segment of size counts[d]; wave-aggregated atomic on total.
__global__ __launch_bounds__(256) void k_alloc(
    const int* __restrict__ counts, int* __restrict__ rowstart, int* __restrict__ total, int N)
{
    int i = blockIdx.x * 256 + threadIdx.x;
    int lane = threadIdx.x & 63;
    int c = (i < N) ? counts[i] : 0;
    int s = c;
    for (int off = 1; off < 64; off <<= 1) {
        int t = __shfl_up(s, off);
        if (lane >= off) s += t;
    }
    int excl = s - c;
    int wavetot = __shfl(s, 63);
    int base = 0;
    if (lane == 63) base = atomicAdd(total, wavetot);
    base = __shfl(base, 63);
    if (i < N) rowstart[i] = base + excl;
}

// ---------------- CSR build: scatter src into dst-sorted order ----------------------
__global__ __launch_bounds__(256) void k_scatter(
    const int* __restrict__ ei, const int* __restrict__ rowstart,
    int* __restrict__ cursor, int* __restrict__ ssrc, int E, int N)
{
    int e = blockIdx.x * 256 + threadIdx.x;
    int tot = E + N;
    if (e >= tot) return;
    int s, d;
    if (e < E) { s = ei[e]; d = ei[E + e]; } else { s = d = e - E; }
    int pos = atomicAdd(&cursor[d], 1);
    ssrc[rowstart[d] + pos] = s;
}

// ---------------- fused GAT layer 1 (C=64): one wave per dst node -------------------
__global__ __launch_bounds__(256) void k_gat1(
    const int* __restrict__ rowstart, const int* __restrict__ counts,
    const int* __restrict__ ssrc,
    const float* __restrict__ as, const float* __restrict__ ad,
    const float* __restrict__ h, float* __restrict__ outp, int N)
{
    int wid = (blockIdx.x * 256 + threadIdx.x) >> 6;   // node
    int lane = threadIdx.x & 63;                       // channel
    if (wid >= N) return;
    int start = rowstart[wid];
    int deg   = counts[wid];
    float adv = ad[wid];
    float acc = 0.f, den = 0.f;
    int s = ssrc[start];
    for (int j = 0; j < deg; ++j) {
        int snext = (j + 1 < deg) ? ssrc[start + j + 1] : 0;
        float v = as[s] + adv;
        v = (v > 0.f) ? v : 0.2f * v;
        float w = __expf(v);
        den += w;
        acc += w * h[(size_t)s * HID + lane];
        s = snext;
    }
    outp[(size_t)wid * HID + lane] = acc / (den + 1e-16f);
}

// ---------------- K4: relu(out1+b1) @ W2 ; as2/ad2 -----------------------------------
__global__ __launch_bounds__(256) void k4_gemm2(
    const float* __restrict__ out1, const float* __restrict__ b1,
    const float* __restrict__ W2, const float* __restrict__ a_src, const float* __restrict__ a_dst,
    float* __restrict__ h2, float* __restrict__ as2, float* __restrict__ ad2, int N)
{
    __shared__ float Wlds[HID * OUTC];   // 4 KB
    __shared__ float rlds[16 * HID];     // 4 KB
    int tid = threadIdx.x;
    for (int i = tid; i < HID * OUTC; i += 256) Wlds[i] = W2[i];
    int row0 = blockIdx.x * 16;
    for (int i = tid; i < 16 * HID; i += 256) {
        int r = row0 + (i >> 6);
        float v = (r < N) ? out1[(size_t)r * HID + (i & 63)] : 0.f;
        v += b1[i & 63];
        rlds[i] = fmaxf(v, 0.f);
    }
    __syncthreads();
    int col = tid & 15;
    int rl  = tid >> 4;
    int row = row0 + rl;
    float acc = 0.f;
    #pragma unroll 8
    for (int k = 0; k < HID; ++k)
        acc += rlds[rl * HID + k] * Wlds[k * OUTC + col];
    if (row < N) {
        h2[(size_t)row * OUTC + col] = acc;
        float vs = acc * a_src[col];
        float vd = acc * a_dst[col];
        for (int off = 8; off > 0; off >>= 1) {
            vs += __shfl_down(vs, off, 16);
            vd += __shfl_down(vd, off, 16);
        }
        if (col == 0) { as2[row] = vs; ad2[row] = vd; }
    }
}

// ---------------- fused GAT layer 2 (C=16): wave per node, 4 edges in flight --------
__global__ __launch_bounds__(256) void k_gat2(
    const int* __restrict__ rowstart, const int* __restrict__ counts,
    const int* __restrict__ ssrc,
    const float* __restrict__ as, const float* __restrict__ ad,
    const float* __restrict__ h, float* __restrict__ outp, int N)
{
    int wid = (blockIdx.x * 256 + threadIdx.x) >> 6;   // node
    int lane = threadIdx.x & 63;
    int c  = lane & 15;       // channel
    int eo = lane >> 4;       // edge subgroup 0..3
    if (wid >= N) return;
    int start = rowstart[wid];
    int deg   = counts[wid];
    float adv = ad[wid];
    float acc = 0.f, den = 0.f;
    for (int j = eo; j < deg; j += 4) {
        int s = ssrc[start + j];
        float v = as[s] + adv;
        v = (v > 0.f) ? v : 0.2f * v;
        float w = __expf(v);
        den += w;
        acc += w * h[(size_t)s * OUTC + c];
    }
    // combine the 4 edge subgroups
    acc += __shfl_xor(acc, 16); den += __shfl_xor(den, 16);
    acc += __shfl_xor(acc, 32); den += __shfl_xor(den, 32);
    if (eo == 0) outp[(size_t)wid * OUTC + c] = acc / (den + 1e-16f);
}

// ---------------- K7: per-node MLP 16->64->16 + softmax ------------------------------
__global__ __launch_bounds__(256) void k7_mlp(
    const float* __restrict__ out2, const float* __restrict__ b2,
    const float* __restrict__ lin1W, const float* __restrict__ lin1b,
    const float* __restrict__ lin2W, const float* __restrict__ lin2b,
    float* __restrict__ out, int N)
{
    __shared__ float W1l[OUTC * HID];   // 4 KB
    __shared__ float W2l[HID * OUTC];   // 4 KB
    __shared__ float b1l[HID], bb2[OUTC], b2l[OUTC];
    int tid = threadIdx.x;
    for (int i = tid; i < OUTC * HID; i += 256) { W1l[i] = lin1W[i]; W2l[i] = lin2W[i]; }
    if (tid < HID) b1l[tid] = lin1b[tid];
    if (tid < OUTC) { bb2[tid] = b2[tid]; b2l[tid] = lin2b[tid]; }
    __syncthreads();
    int n = blockIdx.x * 256 + tid;
    if (n >= N) return;

    float o[OUTC];
    const float4* o4 = (const float4*)(out2 + (size_t)n * OUTC);
    #pragma unroll
    for (int i = 0; i < 4; ++i) {
        float4 v = o4[i];
        o[4*i+0] = v.x + bb2[4*i+0];
        o[4*i+1] = v.y + bb2[4*i+1];
        o[4*i+2] = v.z + bb2[4*i+2];
        o[4*i+3] = v.w + bb2[4*i+3];
    }
    float u[OUTC];
    #pragma unroll
    for (int c = 0; c < OUTC; ++c) u[c] = b2l[c];
    for (int j = 0; j < HID; ++j) {
        float t = b1l[j];
        #pragma unroll
        for (int i = 0; i < OUTC; ++i) t += o[i] * W1l[i * HID + j];
        t = fmaxf(t, 0.f);
        #pragma unroll
        for (int c = 0; c < OUTC; ++c) u[c] += t * W2l[j * OUTC + c];
    }
    float m = u[0];
    #pragma unroll
    for (int c = 1; c < OUTC; ++c) m = fmaxf(m, u[c]);
    float sum = 0.f;
    #pragma unroll
    for (int c = 0; c < OUTC; ++c) { u[c] = __expf(u[c] - m); sum += u[c]; }
    float inv = 1.f / sum;
    float4* dst4 = (float4*)(out + (size_t)n * OUTC);
    #pragma unroll
    for (int i = 0; i < 4; ++i) {
        float4 v;
        v.x = u[4*i+0] * inv; v.y = u[4*i+1] * inv;
        v.z = u[4*i+2] * inv; v.w = u[4*i+3] * inv;
        dst4[i] = v;
    }
}

extern "C" void kernel_launch(void* const* d_in, const int* in_sizes, int n_in,
                              void* d_out, int out_size, void* d_ws, size_t ws_size,
                              hipStream_t stream)
{
    const float* x      = (const float*)d_in[0];
    const int*   ei     = (const int*)  d_in[1];
    const float* W1     = (const float*)d_in[2];
    const float* a_src1 = (const float*)d_in[3];
    const float* a_dst1 = (const float*)d_in[4];
    const float* b1     = (const float*)d_in[5];
    const float* W2     = (const float*)d_in[6];
    const float* a_src2 = (const float*)d_in[7];
    const float* a_dst2 = (const float*)d_in[8];
    const float* b2     = (const float*)d_in[9];
    const float* lin1W  = (const float*)d_in[10];
    const float* lin1b  = (const float*)d_in[11];
    const float* lin2W  = (const float*)d_in[12];
    const float* lin2b  = (const float*)d_in[13];
    float* out = (float*)d_out;

    int N = in_sizes[0] / FIN;
    int E = in_sizes[1] / 2;
    int tot = E + N;

    float* ws = (float*)d_ws;
    size_t off = 0;
    float* h1    = ws + off; off += (size_t)N * HID;
    float* out1  = ws + off; off += (size_t)N * HID;
    float* as1   = ws + off; off += N;
    float* ad1   = ws + off; off += N;
    float* h2    = ws + off; off += (size_t)N * OUTC;
    float* out2  = ws + off; off += (size_t)N * OUTC;
    float* as2   = ws + off; off += N;
    float* ad2   = ws + off; off += N;
    // int region: [counts N][cursor N][total 1][rowstart N][ssrc tot]
    int* counts   = (int*)(ws + off); off += N;
    int* cursor   = (int*)(ws + off); off += N;
    int* total    = (int*)(ws + off); off += 1;
    int* rowstart = (int*)(ws + off); off += N;
    int* ssrc     = (int*)(ws + off); off += tot;

    // zero counts+cursor+total in one shot (contiguous)
    hipMemsetAsync(counts, 0, (size_t)(2 * N + 1) * sizeof(int), stream);

    // CSR build (shared by both layers)
    k_hist   <<<(tot + 255) / 256, 256, 0, stream>>>(ei, counts, E, N);
    k_alloc  <<<(N + 255) / 256, 256, 0, stream>>>(counts, rowstart, total, N);
    k_scatter<<<(tot + 255) / 256, 256, 0, stream>>>(ei, rowstart, cursor, ssrc, E, N);

    // layer 1
    k1_gemm1<<<(N + 3) / 4, 256, 0, stream>>>(x, W1, a_src1, a_dst1, h1, as1, ad1, N);
    k_gat1  <<<(N + 3) / 4, 256, 0, stream>>>(rowstart, counts, ssrc, as1, ad1, h1, out1, N);

    // layer 2
    k4_gemm2<<<(N + 15) / 16, 256, 0, stream>>>(out1, b1, W2, a_src2, a_dst2, h2, as2, ad2, N);
    k_gat2  <<<(N + 3) / 4, 256, 0, stream>>>(rowstart, counts, ssrc, as2, ad2, h2, out2, N);

    // MLP + softmax
    k7_mlp<<<(N + 255) / 256, 256, 0, stream>>>(out2, b2, lin1W, lin1b, lin2W, lin2b, out, N);
}

// Round 7
// 504.499 us; speedup vs baseline: 1.7847x; 1.3561x over previous
//
#include <hip/hip_runtime.h>

#define FIN 128
#define HID 64
#define OUTC 16
#define R1 16

// ---------------- K1: h1 = x @ W1 ; as1/ad1 = rowdot(h1, a_src/a_dst) ----------------
__global__ __launch_bounds__(256) void k1_gemm1(
    const float* __restrict__ x, const float* __restrict__ W1,
    const float* __restrict__ a_src, const float* __restrict__ a_dst,
    float* __restrict__ h1, float* __restrict__ as1, float* __restrict__ ad1, int N)
{
    __shared__ float Wlds[FIN * HID];   // 32 KB
    __shared__ float xlds[R1 * FIN];    // 8 KB
    int tid = threadIdx.x;
    const float4* W4 = (const float4*)W1;
    float4* Wl4 = (float4*)Wlds;
    #pragma unroll
    for (int i = tid; i < FIN * HID / 4; i += 256) Wl4[i] = W4[i];
    int row0 = blockIdx.x * R1;
    const float4* x4 = (const float4*)(x + (size_t)row0 * FIN);
    float4* xl4 = (float4*)xlds;
    for (int i = tid; i < R1 * FIN / 4; i += 256) {
        int r = row0 + (i >> 5);
        xl4[i] = (r < N) ? x4[i] : make_float4(0.f, 0.f, 0.f, 0.f);
    }
    __syncthreads();
    int col = tid & 63;
    int wv  = tid >> 6;        // 0..3, each wave owns 4 rows
    float acc[4] = {0.f, 0.f, 0.f, 0.f};
    #pragma unroll 4
    for (int k = 0; k < FIN; ++k) {
        float w = Wlds[k * HID + col];
        #pragma unroll
        for (int r = 0; r < 4; ++r)
            acc[r] += xlds[(wv * 4 + r) * FIN + k] * w;
    }
    #pragma unroll
    for (int r = 0; r < 4; ++r) {
        int row = row0 + wv * 4 + r;
        if (row < N) {
            h1[(size_t)row * HID + col] = acc[r];
            float vs = acc[r] * a_src[col];
            float vd = acc[r] * a_dst[col];
            for (int off = 32; off > 0; off >>= 1) {
                vs += __shfl_down(vs, off);
                vd += __shfl_down(vd, off);
            }
            if (col == 0) { as1[row] = vs; ad1[row] = vd; }
        }
    }
}

// ---------------- CSR build: histogram of dst --------------------------------------
__global__ __launch_bounds__(256) void k_hist(
    const int* __restrict__ ei, int* __restrict__ counts, int E, int N)
{
    int e = blockIdx.x * 256 + threadIdx.x;
    int tot = E + N;
    if (e >= tot) return;
    int d = (e < E) ? ei[E + e] : (e - E);
    atomicAdd(&counts[d], 1);
}

// ---------------- CSR build: segment allocation (order-free "scan") -----------------
__global__ __launch_bounds__(256) void k_alloc(
    const int* __restrict__ counts, int* __restrict__ rowstart, int* __restrict__ total, int N)
{
    int i = blockIdx.x * 256 + threadIdx.x;
    int lane = threadIdx.x & 63;
    int c = (i < N) ? counts[i] : 0;
    int s = c;
    for (int off = 1; off < 64; off <<= 1) {
        int t = __shfl_up(s, off);
        if (lane >= off) s += t;
    }
    int excl = s - c;
    int wavetot = __shfl(s, 63);
    int base = 0;
    if (lane == 63) base = atomicAdd(total, wavetot);
    base = __shfl(base, 63);
    if (i < N) rowstart[i] = base + excl;
}

// ---------------- CSR build: scatter src into dst-sorted order ----------------------
__global__ __launch_bounds__(256) void k_scatter(
    const int* __restrict__ ei, const int* __restrict__ rowstart,
    int* __restrict__ cursor, int* __restrict__ ssrc, int E, int N)
{
    int e = blockIdx.x * 256 + threadIdx.x;
    int tot = E + N;
    if (e >= tot) return;
    int s, d;
    if (e < E) { s = ei[e]; d = ei[E + e]; } else { s = d = e - E; }
    int pos = atomicAdd(&cursor[d], 1);
    ssrc[rowstart[d] + pos] = s;
}

// ---------------- fused GAT layer 1 (C=64): wave per node, 4 edges in flight --------
__global__ __launch_bounds__(256) void k_gat1(
    const int* __restrict__ rowstart, const int* __restrict__ counts,
    const int* __restrict__ ssrc,
    const float* __restrict__ as, const float* __restrict__ ad,
    const float* __restrict__ h, float* __restrict__ outp, int N)
{
    int wid = (blockIdx.x * 256 + threadIdx.x) >> 6;   // node
    int lane = threadIdx.x & 63;                       // channel
    if (wid >= N) return;
    int start = rowstart[wid];
    int deg   = counts[wid];
    float adv = ad[wid];
    float acc = 0.f, den = 0.f;
    int j = 0;
    for (; j + 4 <= deg; j += 4) {
        int s0 = ssrc[start + j + 0];
        int s1 = ssrc[start + j + 1];
        int s2 = ssrc[start + j + 2];
        int s3 = ssrc[start + j + 3];
        float a0 = as[s0], a1 = as[s1], a2 = as[s2], a3 = as[s3];
        float h0 = h[(size_t)s0 * HID + lane];
        float h1v = h[(size_t)s1 * HID + lane];
        float h2v = h[(size_t)s2 * HID + lane];
        float h3v = h[(size_t)s3 * HID + lane];
        float v0 = a0 + adv; v0 = (v0 > 0.f) ? v0 : 0.2f * v0; float w0 = __expf(v0);
        float v1 = a1 + adv; v1 = (v1 > 0.f) ? v1 : 0.2f * v1; float w1 = __expf(v1);
        float v2 = a2 + adv; v2 = (v2 > 0.f) ? v2 : 0.2f * v2; float w2 = __expf(v2);
        float v3 = a3 + adv; v3 = (v3 > 0.f) ? v3 : 0.2f * v3; float w3 = __expf(v3);
        den += (w0 + w1) + (w2 + w3);
        acc += w0 * h0;
        acc += w1 * h1v;
        acc += w2 * h2v;
        acc += w3 * h3v;
    }
    for (; j < deg; ++j) {
        int s = ssrc[start + j];
        float v = as[s] + adv;
        v = (v > 0.f) ? v : 0.2f * v;
        float w = __expf(v);
        den += w;
        acc += w * h[(size_t)s * HID + lane];
    }
    outp[(size_t)wid * HID + lane] = acc / (den + 1e-16f);
}

// ---------------- K4: relu(out1+b1) @ W2 ; as2/ad2 -----------------------------------
__global__ __launch_bounds__(256) void k4_gemm2(
    const float* __restrict__ out1, const float* __restrict__ b1,
    const float* __restrict__ W2, const float* __restrict__ a_src, const float* __restrict__ a_dst,
    float* __restrict__ h2, float* __restrict__ as2, float* __restrict__ ad2, int N)
{
    __shared__ float Wlds[HID * OUTC];   // 4 KB
    __shared__ float rlds[16 * HID];     // 4 KB
    int tid = threadIdx.x;
    for (int i = tid; i < HID * OUTC; i += 256) Wlds[i] = W2[i];
    int row0 = blockIdx.x * 16;
    for (int i = tid; i < 16 * HID; i += 256) {
        int r = row0 + (i >> 6);
        float v = (r < N) ? out1[(size_t)r * HID + (i & 63)] : 0.f;
        v += b1[i & 63];
        rlds[i] = fmaxf(v, 0.f);
    }
    __syncthreads();
    int col = tid & 15;
    int rl  = tid >> 4;
    int row = row0 + rl;
    float acc = 0.f;
    #pragma unroll 8
    for (int k = 0; k < HID; ++k)
        acc += rlds[rl * HID + k] * Wlds[k * OUTC + col];
    if (row < N) {
        h2[(size_t)row * OUTC + col] = acc;
        float vs = acc * a_src[col];
        float vd = acc * a_dst[col];
        for (int off = 8; off > 0; off >>= 1) {
            vs += __shfl_down(vs, off, 16);
            vd += __shfl_down(vd, off, 16);
        }
        if (col == 0) { as2[row] = vs; ad2[row] = vd; }
    }
}

// ---------------- fused GAT layer 2 (C=16): wave per node, 8 edges in flight --------
__global__ __launch_bounds__(256) void k_gat2(
    const int* __restrict__ rowstart, const int* __restrict__ counts,
    const int* __restrict__ ssrc,
    const float* __restrict__ as, const float* __restrict__ ad,
    const float* __restrict__ h, float* __restrict__ outp, int N)
{
    int wid = (blockIdx.x * 256 + threadIdx.x) >> 6;   // node
    int lane = threadIdx.x & 63;
    int c  = lane & 15;       // channel
    int eo = lane >> 4;       // edge subgroup 0..3
    if (wid >= N) return;
    int start = rowstart[wid];
    int deg   = counts[wid];
    float adv = ad[wid];
    float acc = 0.f, den = 0.f;
    int j = eo;
    for (; j + 4 < deg; j += 8) {
        int s0 = ssrc[start + j];
        int s1 = ssrc[start + j + 4];
        float a0 = as[s0], a1 = as[s1];
        float h0 = h[(size_t)s0 * OUTC + c];
        float h1v = h[(size_t)s1 * OUTC + c];
        float v0 = a0 + adv; v0 = (v0 > 0.f) ? v0 : 0.2f * v0; float w0 = __expf(v0);
        float v1 = a1 + adv; v1 = (v1 > 0.f) ? v1 : 0.2f * v1; float w1 = __expf(v1);
        den += w0 + w1;
        acc += w0 * h0;
        acc += w1 * h1v;
    }
    if (j < deg) {
        int s = ssrc[start + j];
        float v = as[s] + adv;
        v = (v > 0.f) ? v : 0.2f * v;
        float w = __expf(v);
        den += w;
        acc += w * h[(size_t)s * OUTC + c];
    }
    // combine the 4 edge subgroups
    acc += __shfl_xor(acc, 16); den += __shfl_xor(den, 16);
    acc += __shfl_xor(acc, 32); den += __shfl_xor(den, 32);
    if (eo == 0) outp[(size_t)wid * OUTC + c] = acc / (den + 1e-16f);
}

// ---------------- K7: per-node MLP 16->64->16 + softmax ------------------------------
__global__ __launch_bounds__(256) void k7_mlp(
    const float* __restrict__ out2, const float* __restrict__ b2,
    const float* __restrict__ lin1W, const float* __restrict__ lin1b,
    const float* __restrict__ lin2W, const float* __restrict__ lin2b,
    float* __restrict__ out, int N)
{
    __shared__ float W1l[OUTC * HID];   // 4 KB
    __shared__ float W2l[HID * OUTC];   // 4 KB
    __shared__ float b1l[HID], bb2[OUTC], b2l[OUTC];
    int tid = threadIdx.x;
    for (int i = tid; i < OUTC * HID; i += 256) { W1l[i] = lin1W[i]; W2l[i] = lin2W[i]; }
    if (tid < HID) b1l[tid] = lin1b[tid];
    if (tid < OUTC) { bb2[tid] = b2[tid]; b2l[tid] = lin2b[tid]; }
    __syncthreads();
    int n = blockIdx.x * 256 + tid;
    if (n >= N) return;

    float o[OUTC];
    const float4* o4 = (const float4*)(out2 + (size_t)n * OUTC);
    #pragma unroll
    for (int i = 0; i < 4; ++i) {
        float4 v = o4[i];
        o[4*i+0] = v.x + bb2[4*i+0];
        o[4*i+1] = v.y + bb2[4*i+1];
        o[4*i+2] = v.z + bb2[4*i+2];
        o[4*i+3] = v.w + bb2[4*i+3];
    }
    float u[OUTC];
    #pragma unroll
    for (int c = 0; c < OUTC; ++c) u[c] = b2l[c];
    for (int j = 0; j < HID; ++j) {
        float t = b1l[j];
        #pragma unroll
        for (int i = 0; i < OUTC; ++i) t += o[i] * W1l[i * HID + j];
        t = fmaxf(t, 0.f);
        #pragma unroll
        for (int c = 0; c < OUTC; ++c) u[c] += t * W2l[j * OUTC + c];
    }
    float m = u[0];
    #pragma unroll
    for (int c = 1; c < OUTC; ++c) m = fmaxf(m, u[c]);
    float sum = 0.f;
    #pragma unroll
    for (int c = 0; c < OUTC; ++c) { u[c] = __expf(u[c] - m); sum += u[c]; }
    float inv = 1.f / sum;
    float4* dst4 = (float4*)(out + (size_t)n * OUTC);
    #pragma unroll
    for (int i = 0; i < 4; ++i) {
        float4 v;
        v.x = u[4*i+0] * inv; v.y = u[4*i+1] * inv;
        v.z = u[4*i+2] * inv; v.w = u[4*i+3] * inv;
        dst4[i] = v;
    }
}

extern "C" void kernel_launch(void* const* d_in, const int* in_sizes, int n_in,
                              void* d_out, int out_size, void* d_ws, size_t ws_size,
                              hipStream_t stream)
{
    const float* x      = (const float*)d_in[0];
    const int*   ei     = (const int*)  d_in[1];
    const float* W1     = (const float*)d_in[2];
    const float* a_src1 = (const float*)d_in[3];
    const float* a_dst1 = (const float*)d_in[4];
    const float* b1     = (const float*)d_in[5];
    const float* W2     = (const float*)d_in[6];
    const float* a_src2 = (const float*)d_in[7];
    const float* a_dst2 = (const float*)d_in[8];
    const float* b2     = (const float*)d_in[9];
    const float* lin1W  = (const float*)d_in[10];
    const float* lin1b  = (const float*)d_in[11];
    const float* lin2W  = (const float*)d_in[12];
    const float* lin2b  = (const float*)d_in[13];
    float* out = (float*)d_out;

    int N = in_sizes[0] / FIN;
    int E = in_sizes[1] / 2;
    int tot = E + N;

    float* ws = (float*)d_ws;
    size_t off = 0;
    float* h1    = ws + off; off += (size_t)N * HID;
    float* out1  = ws + off; off += (size_t)N * HID;
    float* as1   = ws + off; off += N;
    float* ad1   = ws + off; off += N;
    float* h2    = ws + off; off += (size_t)N * OUTC;
    float* out2  = ws + off; off += (size_t)N * OUTC;
    float* as2   = ws + off; off += N;
    float* ad2   = ws + off; off += N;
    // int region: [counts N][cursor N][total 1][rowstart N][ssrc tot]
    int* counts   = (int*)(ws + off); off += N;
    int* cursor   = (int*)(ws + off); off += N;
    int* total    = (int*)(ws + off); off += 1;
    int* rowstart = (int*)(ws + off); off += N;
    int* ssrc     = (int*)(ws + off); off += tot;

    // zero counts+cursor+total in one shot (contiguous)
    hipMemsetAsync(counts, 0, (size_t)(2 * N + 1) * sizeof(int), stream);

    // CSR build (shared by both layers)
    k_hist   <<<(tot + 255) / 256, 256, 0, stream>>>(ei, counts, E, N);
    k_alloc  <<<(N + 255) / 256, 256, 0, stream>>>(counts, rowstart, total, N);
    k_scatter<<<(tot + 255) / 256, 256, 0, stream>>>(ei, rowstart, cursor, ssrc, E, N);

    // layer 1
    k1_gemm1<<<(N + R1 - 1) / R1, 256, 0, stream>>>(x, W1, a_src1, a_dst1, h1, as1, ad1, N);
    k_gat1  <<<(N + 3) / 4, 256, 0, stream>>>(rowstart, counts, ssrc, as1, ad1, h1, out1, N);

    // layer 2
    k4_gemm2<<<(N + 15) / 16, 256, 0, stream>>>(out1, b1, W2, a_src2, a_dst2, h2, as2, ad2, N);
    k_gat2  <<<(N + 3) / 4, 256, 0, stream>>>(rowstart, counts, ssrc, as2, ad2, h2, out2, N);

    // MLP + softmax
    k7_mlp<<<(N + 255) / 256, 256, 0, stream>>>(out2, b2, lin1W, lin1b, lin2W, lin2b, out, N);
}

// Round 9
// 384.421 us; speedup vs baseline: 2.3422x; 1.3124x over previous
//
#include <hip/hip_runtime.h>

#define FIN 128
#define HID 64
#define OUTC 16
#define R1 16
#define BSH 8              // 256 nodes per bucket
#define MAXNB 512          // supports N <= 131072

// ---------------- K1: h1 = x @ W1 ; as1/ad1 = rowdot(h1, a_src/a_dst) ----------------
__global__ __launch_bounds__(256) void k1_gemm1(
    const float* __restrict__ x, const float* __restrict__ W1,
    const float* __restrict__ a_src, const float* __restrict__ a_dst,
    float* __restrict__ h1, float* __restrict__ as1, float* __restrict__ ad1, int N)
{
    __shared__ float Wlds[FIN * HID];   // 32 KB
    __shared__ float xlds[R1 * FIN];    // 8 KB
    int tid = threadIdx.x;
    const float4* W4 = (const float4*)W1;
    float4* Wl4 = (float4*)Wlds;
    #pragma unroll
    for (int i = tid; i < FIN * HID / 4; i += 256) Wl4[i] = W4[i];
    int row0 = blockIdx.x * R1;
    const float4* x4 = (const float4*)(x + (size_t)row0 * FIN);
    float4* xl4 = (float4*)xlds;
    for (int i = tid; i < R1 * FIN / 4; i += 256) {
        int r = row0 + (i >> 5);
        xl4[i] = (r < N) ? x4[i] : make_float4(0.f, 0.f, 0.f, 0.f);
    }
    __syncthreads();
    int col = tid & 63;
    int wv  = tid >> 6;        // 0..3, each wave owns 4 rows
    float acc[4] = {0.f, 0.f, 0.f, 0.f};
    #pragma unroll 4
    for (int k = 0; k < FIN; ++k) {
        float w = Wlds[k * HID + col];
        #pragma unroll
        for (int r = 0; r < 4; ++r)
            acc[r] += xlds[(wv * 4 + r) * FIN + k] * w;
    }
    #pragma unroll
    for (int r = 0; r < 4; ++r) {
        int row = row0 + wv * 4 + r;
        if (row < N) {
            h1[(size_t)row * HID + col] = acc[r];
            float vs = acc[r] * a_src[col];
            float vd = acc[r] * a_dst[col];
            for (int off = 32; off > 0; off >>= 1) {
                vs += __shfl_down(vs, off);
                vd += __shfl_down(vd, off);
            }
            if (col == 0) { as1[row] = vs; ad1[row] = vd; }
        }
    }
}

// ---------------- bucket CSR build, phase 1: bucket histogram -----------------------
__global__ __launch_bounds__(256) void kp_cnt(
    const int* __restrict__ ei, int* __restrict__ bcnt, int E, int N)
{
    __shared__ int h[MAXNB];
    int tot = E + N;
    for (int i = threadIdx.x; i < MAXNB; i += 256) h[i] = 0;
    __syncthreads();
    int t0 = blockIdx.x * 4096;
    int n = min(4096, tot - t0);
    for (int i = threadIdx.x; i < n; i += 256) {
        int e = t0 + i;
        int d = (e < E) ? ei[E + e] : (e - E);
        atomicAdd(&h[d >> BSH], 1);
    }
    __syncthreads();
    int nb = (N + 255) >> BSH;
    for (int b = threadIdx.x; b < nb; b += 256)
        if (h[b]) atomicAdd(&bcnt[b], h[b]);
}

// ---------------- phase 2: scan bucket counts ---------------------------------------
__global__ __launch_bounds__(512) void kp_scan(
    const int* __restrict__ bcnt, int* __restrict__ bstartE, int* __restrict__ bcur, int N)
{
    __shared__ int sA[512], sB[512];
    int nb = (N + 255) >> BSH;
    int tid = threadIdx.x;
    int c = (tid < nb) ? bcnt[tid] : 0;
    sA[tid] = c;
    __syncthreads();
    int* src = sA; int* dst = sB;
    for (int off = 1; off < 512; off <<= 1) {
        int v = src[tid];
        if (tid >= off) v += src[tid - off];
        dst[tid] = v;
        __syncthreads();
        int* t = src; src = dst; dst = t;
    }
    int incl = src[tid];
    int excl = incl - c;
    if (tid < nb) {
        bstartE[tid] = excl;
        bcur[tid] = excl;
        if (tid == nb - 1) bstartE[nb] = incl;
    }
}

// ---------------- phase 3: tiled multi-split partition into bucket pair lists -------
__global__ __launch_bounds__(256) void kp_part(
    const int* __restrict__ ei, int* __restrict__ bcur, uint2* __restrict__ pairs,
    int E, int N)
{
    __shared__ int sL[4096], dL[4096];               // 32 KB
    __shared__ int cnt[MAXNB], base[MAXNB], wcur[MAXNB];
    int tot = E + N;
    for (int i = threadIdx.x; i < MAXNB; i += 256) { cnt[i] = 0; wcur[i] = 0; }
    int t0 = blockIdx.x * 4096;
    int n = min(4096, tot - t0);
    for (int i = threadIdx.x; i < n; i += 256) {
        int e = t0 + i; int s, d;
        if (e < E) { s = ei[e]; d = ei[E + e]; } else { s = d = e - E; }
        sL[i] = s; dL[i] = d;
    }
    __syncthreads();
    for (int i = threadIdx.x; i < n; i += 256) atomicAdd(&cnt[dL[i] >> BSH], 1);
    __syncthreads();
    int nb = (N + 255) >> BSH;
    for (int b = threadIdx.x; b < nb; b += 256) {
        int c = cnt[b];
        if (c) base[b] = atomicAdd(&bcur[b], c);
    }
    __syncthreads();
    for (int i = threadIdx.x; i < n; i += 256) {
        int b = dL[i] >> BSH;
        int r = atomicAdd(&wcur[b], 1);
        pairs[base[b] + r] = make_uint2((unsigned)sL[i], (unsigned)dL[i]);
    }
}

// ---------------- phase 4: per-bucket fine scatter + rowstart/counts ----------------
__global__ __launch_bounds__(256) void kc_fine(
    const uint2* __restrict__ pairs, const int* __restrict__ bstartE,
    int* __restrict__ rowstart, int* __restrict__ counts, int* __restrict__ ssrc, int N)
{
    __shared__ int ncnt[256], nsA[256], nsB[256], nst[256];
    int blk = blockIdx.x, tid = threadIdx.x;
    int node0 = blk << BSH;
    int e0 = bstartE[blk], e1 = bstartE[blk + 1];
    ncnt[tid] = 0;
    __syncthreads();
    for (int i = e0 + tid; i < e1; i += 256)
        atomicAdd(&ncnt[pairs[i].y - node0], 1);
    __syncthreads();
    int c = ncnt[tid];
    nsA[tid] = c;
    __syncthreads();
    int* s = nsA; int* d = nsB;
    for (int off = 1; off < 256; off <<= 1) {
        int v = s[tid];
        if (tid >= off) v += s[tid - off];
        d[tid] = v;
        __syncthreads();
        int* t = s; s = d; d = t;
    }
    int excl = s[tid] - c;
    int node = node0 + tid;
    if (node < N) { rowstart[node] = e0 + excl; counts[node] = c; }
    __syncthreads();
    nst[tid] = excl;
    ncnt[tid] = 0;
    __syncthreads();
    for (int i = e0 + tid; i < e1; i += 256) {
        uint2 p = pairs[i];
        int dl = (int)p.y - node0;
        int r = atomicAdd(&ncnt[dl], 1);
        ssrc[e0 + nst[dl] + r] = (int)p.x;
    }
}

// ---------------- fused GAT layer 1 (C=64): wave per node, 4 edges in flight --------
__global__ __launch_bounds__(256) void k_gat1(
    const int* __restrict__ rowstart, const int* __restrict__ counts,
    const int* __restrict__ ssrc,
    const float* __restrict__ as, const float* __restrict__ ad,
    const float* __restrict__ h, float* __restrict__ outp, int N)
{
    int wid = (blockIdx.x * 256 + threadIdx.x) >> 6;   // node
    int lane = threadIdx.x & 63;                       // channel
    if (wid >= N) return;
    int start = rowstart[wid];
    int deg   = counts[wid];
    float adv = ad[wid];
    float acc = 0.f, den = 0.f;
    int j = 0;
    for (; j + 4 <= deg; j += 4) {
        int s0 = ssrc[start + j + 0];
        int s1 = ssrc[start + j + 1];
        int s2 = ssrc[start + j + 2];
        int s3 = ssrc[start + j + 3];
        float a0 = as[s0], a1 = as[s1], a2 = as[s2], a3 = as[s3];
        float h0 = h[(size_t)s0 * HID + lane];
        float h1v = h[(size_t)s1 * HID + lane];
        float h2v = h[(size_t)s2 * HID + lane];
        float h3v = h[(size_t)s3 * HID + lane];
        float v0 = a0 + adv; v0 = (v0 > 0.f) ? v0 : 0.2f * v0; float w0 = __expf(v0);
        float v1 = a1 + adv; v1 = (v1 > 0.f) ? v1 : 0.2f * v1; float w1 = __expf(v1);
        float v2 = a2 + adv; v2 = (v2 > 0.f) ? v2 : 0.2f * v2; float w2 = __expf(v2);
        float v3 = a3 + adv; v3 = (v3 > 0.f) ? v3 : 0.2f * v3; float w3 = __expf(v3);
        den += (w0 + w1) + (w2 + w3);
        acc += w0 * h0;
        acc += w1 * h1v;
        acc += w2 * h2v;
        acc += w3 * h3v;
    }
    for (; j < deg; ++j) {
        int s = ssrc[start + j];
        float v = as[s] + adv;
        v = (v > 0.f) ? v : 0.2f * v;
        float w = __expf(v);
        den += w;
        acc += w * h[(size_t)s * HID + lane];
    }
    outp[(size_t)wid * HID + lane] = acc / (den + 1e-16f);
}

// ---------------- K4: relu(out1+b1) @ W2 ; as2/ad2 -----------------------------------
__global__ __launch_bounds__(256) void k4_gemm2(
    const float* __restrict__ out1, const float* __restrict__ b1,
    const float* __restrict__ W2, const float* __restrict__ a_src, const float* __restrict__ a_dst,
    float* __restrict__ h2, float* __restrict__ as2, float* __restrict__ ad2, int N)
{
    __shared__ float Wlds[HID * OUTC];   // 4 KB
    __shared__ float rlds[16 * HID];     // 4 KB
    int tid = threadIdx.x;
    for (int i = tid; i < HID * OUTC; i += 256) Wlds[i] = W2[i];
    int row0 = blockIdx.x * 16;
    for (int i = tid; i < 16 * HID; i += 256) {
        int r = row0 + (i >> 6);
        float v = (r < N) ? out1[(size_t)r * HID + (i & 63)] : 0.f;
        v += b1[i & 63];
        rlds[i] = fmaxf(v, 0.f);
    }
    __syncthreads();
    int col = tid & 15;
    int rl  = tid >> 4;
    int row = row0 + rl;
    float acc = 0.f;
    #pragma unroll 8
    for (int k = 0; k < HID; ++k)
        acc += rlds[rl * HID + k] * Wlds[k * OUTC + col];
    if (row < N) {
        h2[(size_t)row * OUTC + col] = acc;
        float vs = acc * a_src[col];
        float vd = acc * a_dst[col];
        for (int off = 8; off > 0; off >>= 1) {
            vs += __shfl_down(vs, off, 16);
            vd += __shfl_down(vd, off, 16);
        }
        if (col == 0) { as2[row] = vs; ad2[row] = vd; }
    }
}

// ---------------- fused GAT layer 2 (C=16): wave per node, 8 edges in flight --------
__global__ __launch_bounds__(256) void k_gat2(
    const int* __restrict__ rowstart, const int* __restrict__ counts,
    const int* __restrict__ ssrc,
    const float* __restrict__ as, const float* __restrict__ ad,
    const float* __restrict__ h, float* __restrict__ outp, int N)
{
    int wid = (blockIdx.x * 256 + threadIdx.x) >> 6;   // node
    int lane = threadIdx.x & 63;
    int c  = lane & 15;       // channel
    int eo = lane >> 4;       // edge subgroup 0..3
    if (wid >= N) return;
    int start = rowstart[wid];
    int deg   = counts[wid];
    float adv = ad[wid];
    float acc = 0.f, den = 0.f;
    int j = eo;
    for (; j + 4 < deg; j += 8) {
        int s0 = ssrc[start + j];
        int s1 = ssrc[start + j + 4];
        float a0 = as[s0], a1 = as[s1];
        float h0 = h[(size_t)s0 * OUTC + c];
        float h1v = h[(size_t)s1 * OUTC + c];
        float v0 = a0 + adv; v0 = (v0 > 0.f) ? v0 : 0.2f * v0; float w0 = __expf(v0);
        float v1 = a1 + adv; v1 = (v1 > 0.f) ? v1 : 0.2f * v1; float w1 = __expf(v1);
        den += w0 + w1;
        acc += w0 * h0;
        acc += w1 * h1v;
    }
    if (j < deg) {
        int s = ssrc[start + j];
        float v = as[s] + adv;
        v = (v > 0.f) ? v : 0.2f * v;
        float w = __expf(v);
        den += w;
        acc += w * h[(size_t)s * OUTC + c];
    }
    // combine the 4 edge subgroups
    acc += __shfl_xor(acc, 16); den += __shfl_xor(den, 16);
    acc += __shfl_xor(acc, 32); den += __shfl_xor(den, 32);
    if (eo == 0) outp[(size_t)wid * OUTC + c] = acc / (den + 1e-16f);
}

// ---------------- K7: per-node MLP 16->64->16 + softmax ------------------------------
__global__ __launch_bounds__(256) void k7_mlp(
    const float* __restrict__ out2, const float* __restrict__ b2,
    const float* __restrict__ lin1W, const float* __restrict__ lin1b,
    const float* __restrict__ lin2W, const float* __restrict__ lin2b,
    float* __restrict__ out, int N)
{
    __shared__ float W1l[OUTC * HID];   // 4 KB
    __shared__ float W2l[HID * OUTC];   // 4 KB
    __shared__ float b1l[HID], bb2[OUTC], b2l[OUTC];
    int tid = threadIdx.x;
    for (int i = tid; i < OUTC * HID; i += 256) { W1l[i] = lin1W[i]; W2l[i] = lin2W[i]; }
    if (tid < HID) b1l[tid] = lin1b[tid];
    if (tid < OUTC) { bb2[tid] = b2[tid]; b2l[tid] = lin2b[tid]; }
    __syncthreads();
    int n = blockIdx.x * 256 + tid;
    if (n >= N) return;

    float o[OUTC];
    const float4* o4 = (const float4*)(out2 + (size_t)n * OUTC);
    #pragma unroll
    for (int i = 0; i < 4; ++i) {
        float4 v = o4[i];
        o[4*i+0] = v.x + bb2[4*i+0];
        o[4*i+1] = v.y + bb2[4*i+1];
        o[4*i+2] = v.z + bb2[4*i+2];
        o[4*i+3] = v.w + bb2[4*i+3];
    }
    float u[OUTC];
    #pragma unroll
    for (int c = 0; c < OUTC; ++c) u[c] = b2l[c];
    for (int j = 0; j < HID; ++j) {
        float t = b1l[j];
        #pragma unroll
        for (int i = 0; i < OUTC; ++i) t += o[i] * W1l[i * HID + j];
        t = fmaxf(t, 0.f);
        #pragma unroll
        for (int c = 0; c < OUTC; ++c) u[c] += t * W2l[j * OUTC + c];
    }
    float m = u[0];
    #pragma unroll
    for (int c = 1; c < OUTC; ++c) m = fmaxf(m, u[c]);
    float sum = 0.f;
    #pragma unroll
    for (int c = 0; c < OUTC; ++c) { u[c] = __expf(u[c] - m); sum += u[c]; }
    float inv = 1.f / sum;
    float4* dst4 = (float4*)(out + (size_t)n * OUTC);
    #pragma unroll
    for (int i = 0; i < 4; ++i) {
        float4 v;
        v.x = u[4*i+0] * inv; v.y = u[4*i+1] * inv;
        v.z = u[4*i+2] * inv; v.w = u[4*i+3] * inv;
        dst4[i] = v;
    }
}

extern "C" void kernel_launch(void* const* d_in, const int* in_sizes, int n_in,
                              void* d_out, int out_size, void* d_ws, size_t ws_size,
                              hipStream_t stream)
{
    const float* x      = (const float*)d_in[0];
    const int*   ei     = (const int*)  d_in[1];
    const float* W1     = (const float*)d_in[2];
    const float* a_src1 = (const float*)d_in[3];
    const float* a_dst1 = (const float*)d_in[4];
    const float* b1     = (const float*)d_in[5];
    const float* W2     = (const float*)d_in[6];
    const float* a_src2 = (const float*)d_in[7];
    const float* a_dst2 = (const float*)d_in[8];
    const float* b2     = (const float*)d_in[9];
    const float* lin1W  = (const float*)d_in[10];
    const float* lin1b  = (const float*)d_in[11];
    const float* lin2W  = (const float*)d_in[12];
    const float* lin2b  = (const float*)d_in[13];
    float* out = (float*)d_out;

    int N = in_sizes[0] / FIN;
    int E = in_sizes[1] / 2;
    int tot = E + N;
    int nb = (N + 255) >> BSH;
    int ntile = (tot + 4095) / 4096;

    float* ws = (float*)d_ws;
    size_t off = 0;
    float* h1    = ws + off; off += (size_t)N * HID;
    float* out1  = ws + off; off += (size_t)N * HID;   // pairs aliases this region
    float* as1   = ws + off; off += N;
    float* ad1   = ws + off; off += N;
    float* h2    = ws + off; off += (size_t)N * OUTC;
    float* out2  = ws + off; off += (size_t)N * OUTC;
    float* as2   = ws + off; off += N;
    float* ad2   = ws + off; off += N;
    int* rowstart = (int*)(ws + off); off += N;
    int* counts   = (int*)(ws + off); off += N;
    int* ssrc     = (int*)(ws + off); off += tot;
    int* bcnt     = (int*)(ws + off); off += MAXNB;
    int* bstartE  = (int*)(ws + off); off += MAXNB + 1;
    int* bcur     = (int*)(ws + off); off += MAXNB;
    uint2* pairs  = (uint2*)out1;     // 13.6 MB <= 25.6 MB, consumed before k_gat1 writes out1

    hipMemsetAsync(bcnt, 0, (size_t)nb * sizeof(int), stream);

    // bucketed CSR build
    kp_cnt <<<ntile, 256, 0, stream>>>(ei, bcnt, E, N);
    kp_scan<<<1, 512, 0, stream>>>(bcnt, bstartE, bcur, N);
    kp_part<<<ntile, 256, 0, stream>>>(ei, bcur, pairs, E, N);
    kc_fine<<<nb, 256, 0, stream>>>(pairs, bstartE, rowstart, counts, ssrc, N);

    // layer 1
    k1_gemm1<<<(N + R1 - 1) / R1, 256, 0, stream>>>(x, W1, a_src1, a_dst1, h1, as1, ad1, N);
    k_gat1  <<<(N + 3) / 4, 256, 0, stream>>>(rowstart, counts, ssrc, as1, ad1, h1, out1, N);

    // layer 2
    k4_gemm2<<<(N + 15) / 16, 256, 0, stream>>>(out1, b1, W2, a_src2, a_dst2, h2, as2, ad2, N);
    k_gat2  <<<(N + 3) / 4, 256, 0, stream>>>(rowstart, counts, ssrc, as2, ad2, h2, out2, N);

    // MLP + softmax
    k7_mlp<<<(N + 255) / 256, 256, 0, stream>>>(out2, b2, lin1W, lin1b, lin2W, lin2b, out, N);
}